// Round 3
// baseline (334.027 us; speedup 1.0000x reference)
//
#include <hip/hip_runtime.h>
#include <hip/hip_bf16.h>

#define CODE_DIM 256
#define HIDDEN   128
#define HEADS    4
#define N_CODES  100000
#define N_SPEC   256

// ---- k2 config ----
#define K2_BLOCKS 1024
#define K2_TPB    256
#define K2_WPB    4                       // waves per block
#define WROWS     8                       // rows per wave-tile
#define NTILES    (N_CODES / WROWS)       // 12500 exact, no tail
#define RSTRIDE   260                     // padded LDS row stride (floats)
#define NSLOTS    64

// ---- ws layout (floats) ----
#define WS_V       0                       // v[h][d] : 1024
#define WS_CP      1024                    // c partials [64]: block bx = h*16+dseg
#define WS_CTR     1088                    // atomic tile counter (int)
#define WS_SLOT    1104                    // 64 slots x 1028 (16B-aligned)
#define SLOT_STRIDE 1028

// ---- k2 LDS layout (floats) ----
#define LDS_VSH   0                        // 1024
#define LDS_TSH   1024                     // 4 waves x 8 rows x 4 heads = 128
#define LDS_TILE  1152
#define LDS_TOTAL (LDS_TILE + K2_WPB * WROWS * RSTRIDE)   // 9472 floats = 37888 B

// s_waitcnt immediates (gfx9 encoding)
#define WAITCNT_VM0   0x0F70   // vmcnt=0, lgkm=nowait
#define WAITCNT_LGKM0 0xC07F   // lgkm=0, vmcnt=nowait

typedef __attribute__((address_space(1))) const void* as1cv;
typedef __attribute__((address_space(3))) void*       as3v;

// K1 (64 blocks): v[h,d] = W[h,d,:]·a2[h]; c partials; zero slots + counter.
__global__ void k1_prep(const float* __restrict__ pe, const float* __restrict__ W,
                        const float* __restrict__ b, const float* __restrict__ a,
                        float* __restrict__ ws) {
    const int bx = blockIdx.x;            // 64: (h, d-16th)
    const int h = bx >> 4, dseg = bx & 15;
    const int tid = threadIdx.x;
    const int dl = tid >> 4;              // 16 d-values per block
    const int q  = tid & 15;              // 16 k-chunks of 8 elems
    const int d  = dseg * 16 + dl;
    __shared__ float a_sh[2 * HIDDEN];
    __shared__ float cred[4];
    a_sh[tid] = a[h * 2 * HIDDEN + tid];
    __syncthreads();

    const float4* wr = (const float4*)(W + ((size_t)(h * CODE_DIM + d)) * HIDDEN + q * 8);
    float u = 0.f, v = 0.f;
#pragma unroll
    for (int j = 0; j < 2; ++j) {
        float4 wv = wr[j];
        int k = q * 8 + j * 4;
        u += wv.x * a_sh[k]     + wv.y * a_sh[k + 1]
           + wv.z * a_sh[k + 2] + wv.w * a_sh[k + 3];
        v += wv.x * a_sh[HIDDEN + k]     + wv.y * a_sh[HIDDEN + k + 1]
           + wv.z * a_sh[HIDDEN + k + 2] + wv.w * a_sh[HIDDEN + k + 3];
    }
#pragma unroll
    for (int off = 1; off < 16; off <<= 1) {
        u += __shfl_xor(u, off, 64);
        v += __shfl_xor(v, off, 64);
    }
    if (q == 0) ws[WS_V + h * CODE_DIM + d] = v;

    float cp = (q == 0) ? pe[d] * u : 0.f;
    if (dseg == 0 && tid < HIDDEN) cp += b[h * HIDDEN + tid] * (a_sh[tid] + a_sh[HIDDEN + tid]);
#pragma unroll
    for (int off = 32; off; off >>= 1) cp += __shfl_xor(cp, off, 64);
    if ((tid & 63) == 0) cred[tid >> 6] = cp;
    __syncthreads();
    if (tid == 0) ws[WS_CP + bx] = cred[0] + cred[1] + cred[2] + cred[3];
    if (bx == 0 && tid == 0) *(int*)(ws + WS_CTR) = 0;

    // zero the 64 atomic slots (k2 depends on stream order)
    float4* z = (float4*)(ws + WS_SLOT);
    const int g = bx * 256 + tid;                 // 16384 threads
    const int nz = (NSLOTS * SLOT_STRIDE) / 4;    // 16448 float4s
    z[g] = make_float4(0.f, 0.f, 0.f, 0.f);
    if (g + 16384 < nz) z[g + 16384] = make_float4(0.f, 0.f, 0.f, 0.f);
}

// K2: streamed pass over code_embs; work-stealing wave-private LDS tiles.
__global__ __launch_bounds__(K2_TPB, 4) void k2_main(const float* __restrict__ code,
                                                     float* __restrict__ ws) {
    __shared__ float lds[LDS_TOTAL];
    __shared__ float c_sh[HEADS];
    const int tid  = threadIdx.x;
    const int lane = tid & 63;
    const int w    = tid >> 6;
    const int row  = lane >> 3;       // 8 rows per wave-tile
    const int seg  = lane & 7;        // 8 lanes per row, 32 cols each
    const int bx   = blockIdx.x;

    // stage v into LDS; reduce the 64 c-partials
    {
        float4 vv = ((const float4*)(ws + WS_V))[tid];
        *(float4*)&lds[LDS_VSH + tid * 4] = vv;
    }
    if (tid < 64) {
        float cpv = ws[WS_CP + tid];
#pragma unroll
        for (int off = 1; off < 16; off <<= 1) cpv += __shfl_xor(cpv, off, 64);
        if ((tid & 15) == 0) c_sh[tid >> 4] = cpv;
    }
    __syncthreads();
    float ch[HEADS];
#pragma unroll
    for (int h = 0; h < HEADS; ++h) ch[h] = c_sh[h];

    const int tilebase = LDS_TILE + w * (WROWS * RSTRIDE);
    const int xb = tilebase + row * RSTRIDE + seg * 32;
    int* ctr = (int*)(ws + WS_CTR);

    float4 acc0 = make_float4(0,0,0,0), acc1 = acc0, acc2 = acc0, acc3 = acc0;
    float ds0 = 0.f, ds1 = 0.f, ds2 = 0.f, ds3 = 0.f;

    for (;;) {
        int tile;
        if (lane == 0) tile = atomicAdd(ctr, 1);
        tile = __shfl(tile, 0, 64);
        if (tile >= NTILES) break;

        // ensure prior phase-2 LDS reads retired before DMA overwrites the tile
        __builtin_amdgcn_s_waitcnt(WAITCNT_LGKM0);
        const float* gbase = code + (size_t)tile * (WROWS * CODE_DIM) + lane * 4;
#pragma unroll
        for (int r = 0; r < WROWS; ++r) {
            __builtin_amdgcn_global_load_lds((as1cv)(gbase + r * CODE_DIM),
                                             (as3v)&lds[tilebase + r * RSTRIDE], 16, 0, 0);
        }
        __builtin_amdgcn_s_waitcnt(WAITCNT_VM0);

        // phase 1: per-lane partial dots over 32 cols of own row, 3-level butterfly
        float p0 = 0.f, p1 = 0.f, p2 = 0.f, p3 = 0.f;
#pragma unroll
        for (int c = 0; c < 8; ++c) {
            float4 x4 = *(const float4*)&lds[xb + c * 4];
            float4 va = *(const float4*)&lds[LDS_VSH +   0 + seg * 32 + c * 4];
            float4 vb = *(const float4*)&lds[LDS_VSH + 256 + seg * 32 + c * 4];
            float4 vc = *(const float4*)&lds[LDS_VSH + 512 + seg * 32 + c * 4];
            float4 vd = *(const float4*)&lds[LDS_VSH + 768 + seg * 32 + c * 4];
            p0 += x4.x * va.x + x4.y * va.y + x4.z * va.z + x4.w * va.w;
            p1 += x4.x * vb.x + x4.y * vb.y + x4.z * vb.z + x4.w * vb.w;
            p2 += x4.x * vc.x + x4.y * vc.y + x4.z * vc.z + x4.w * vc.w;
            p3 += x4.x * vd.x + x4.y * vd.y + x4.z * vd.z + x4.w * vd.w;
        }
#pragma unroll
        for (int off = 1; off < 8; off <<= 1) {
            p0 += __shfl_xor(p0, off, 64);
            p1 += __shfl_xor(p1, off, 64);
            p2 += __shfl_xor(p2, off, 64);
            p3 += __shfl_xor(p3, off, 64);
        }
        float e0 = p0 + ch[0]; e0 = (e0 >= 0.f) ? e0 : 0.2f * e0; float t0 = __expf(e0);
        float e1 = p1 + ch[1]; e1 = (e1 >= 0.f) ? e1 : 0.2f * e1; float t1 = __expf(e1);
        float e2 = p2 + ch[2]; e2 = (e2 >= 0.f) ? e2 : 0.2f * e2; float t2 = __expf(e2);
        float e3 = p3 + ch[3]; e3 = (e3 >= 0.f) ? e3 : 0.2f * e3; float t3 = __expf(e3);
        ds0 += t0; ds1 += t1; ds2 += t2; ds3 += t3;   // 8x redundant, scaled at write-out
        if (seg == 0) *(float4*)&lds[LDS_TSH + w * 32 + row * 4] = make_float4(t0, t1, t2, t3);
        __builtin_amdgcn_s_waitcnt(WAITCNT_LGKM0);     // t_sh visible to whole wave

        // phase 2: broadcast row + t, accumulate weighted sum (lane owns cols 4l..4l+3)
#pragma unroll
        for (int r = 0; r < WROWS; ++r) {
            float4 tr = *(const float4*)&lds[LDS_TSH + w * 32 + r * 4];
            float4 x4 = *(const float4*)&lds[tilebase + r * RSTRIDE + lane * 4];
            acc0.x += tr.x * x4.x; acc0.y += tr.x * x4.y; acc0.z += tr.x * x4.z; acc0.w += tr.x * x4.w;
            acc1.x += tr.y * x4.x; acc1.y += tr.y * x4.y; acc1.z += tr.y * x4.z; acc1.w += tr.y * x4.w;
            acc2.x += tr.z * x4.x; acc2.y += tr.z * x4.y; acc2.z += tr.z * x4.z; acc2.w += tr.z * x4.w;
            acc3.x += tr.w * x4.x; acc3.y += tr.w * x4.y; acc3.z += tr.w * x4.z; acc3.w += tr.w * x4.w;
        }
    }

    // block-level reduction (reuse LDS), then one atomic slot-add per block
    __syncthreads();
    *(float4*)&lds[w * 1024 +   0 + 4 * lane] = acc0;
    *(float4*)&lds[w * 1024 + 256 + 4 * lane] = acc1;
    *(float4*)&lds[w * 1024 + 512 + 4 * lane] = acc2;
    *(float4*)&lds[w * 1024 + 768 + 4 * lane] = acc3;
    *(float4*)&lds[4096 + (w * 64 + lane) * 4] = make_float4(ds0, ds1, ds2, ds3);
    __syncthreads();

    float* slot = ws + WS_SLOT + (size_t)(bx & (NSLOTS - 1)) * SLOT_STRIDE;
    for (int o = tid; o < HEADS * CODE_DIM; o += K2_TPB) {
        float s = lds[o] + lds[1024 + o] + lds[2048 + o] + lds[3072 + o];
        atomicAdd(slot + o, s);
    }
    {
        const int h = tid >> 6, l2 = tid & 63;
        float dv = lds[4096 +   0 + l2 * 4 + h] + lds[4096 + 256 + l2 * 4 + h]
                 + lds[4096 + 512 + l2 * 4 + h] + lds[4096 + 768 + l2 * 4 + h];
#pragma unroll
        for (int off = 32; off; off >>= 1) dv += __shfl_xor(dv, off, 64);
        if (l2 == 0) atomicAdd(slot + HEADS * CODE_DIM + h, dv * 0.125f);
    }
}

// K3 (16 blocks): reduce slots -> s[h][:]; normalize; GEMV agg = s@W + b -> mho
__global__ void k3_agg(const float* __restrict__ W, const float* __restrict__ b,
                       const float* __restrict__ ws, float* __restrict__ out) {
    const int bx = blockIdx.x;      // (h, k-quarter)
    const int h = bx >> 2, q = bx & 3;
    const int tid = threadIdx.x;
    __shared__ float s_sh[CODE_DIM];
    __shared__ float yred[8 * 32];
    __shared__ float den_sh;
    const float* slots = ws + WS_SLOT;

    if (tid < 64) {
        float dv = slots[(size_t)tid * SLOT_STRIDE + HEADS * CODE_DIM + h];
#pragma unroll
        for (int off = 32; off; off >>= 1) dv += __shfl_xor(dv, off, 64);
        if (tid == 0) den_sh = dv;
    }
    float su = 0.f;
#pragma unroll 8
    for (int s2 = 0; s2 < NSLOTS; ++s2)
        su += slots[(size_t)s2 * SLOT_STRIDE + h * CODE_DIM + tid];
    __syncthreads();
    s_sh[tid] = su / den_sh;
    __syncthreads();

    const int c = tid >> 5, kl = tid & 31;
    float y = 0.f;
    const float* wp = W + ((size_t)(h * CODE_DIM + c * 32)) * HIDDEN + q * 32 + kl;
#pragma unroll 8
    for (int d = 0; d < 32; ++d) y += s_sh[c * 32 + d] * wp[(size_t)d * HIDDEN];
    yred[c * 32 + kl] = y;
    __syncthreads();
    if (tid < 32) {
        float t = 0.f;
#pragma unroll
        for (int cc = 0; cc < 8; ++cc) t += yred[cc * 32 + tid];
        out[N_SPEC + h * HIDDEN + q * 32 + tid] = t + b[h * HIDDEN + q * 32 + tid];
    }
}

// K4: specialty_logits = Wc @ mho + bc; one wave per logit
__global__ void k4_logits(const float* __restrict__ Wc, const float* __restrict__ bc,
                          float* __restrict__ out) {
    const int lane = threadIdx.x & 63;
    const int wv   = threadIdx.x >> 6;
    const int i    = blockIdx.x * 4 + wv;
    const float4* wr  = (const float4*)(Wc + (size_t)i * (HEADS * HIDDEN));
    const float4* mh4 = (const float4*)(out + N_SPEC);
    float4 wa = wr[lane],      ma = mh4[lane];
    float4 wb = wr[64 + lane], mb = mh4[64 + lane];
    float pp = wa.x * ma.x + wa.y * ma.y + wa.z * ma.z + wa.w * ma.w
             + wb.x * mb.x + wb.y * mb.y + wb.z * mb.z + wb.w * mb.w;
#pragma unroll
    for (int off = 32; off; off >>= 1) pp += __shfl_xor(pp, off, 64);
    if (lane == 0) out[i] = pp + bc[i];
}

extern "C" void kernel_launch(void* const* d_in, const int* in_sizes, int n_in,
                              void* d_out, int out_size, void* d_ws, size_t ws_size,
                              hipStream_t stream) {
    const float* pe   = (const float*)d_in[0];
    const float* code = (const float*)d_in[1];
    const float* W    = (const float*)d_in[2];
    const float* b    = (const float*)d_in[3];
    const float* a    = (const float*)d_in[4];
    const float* Wc   = (const float*)d_in[5];
    const float* bc   = (const float*)d_in[6];
    float* out = (float*)d_out;
    float* ws  = (float*)d_ws;

    k1_prep<<<64, 256, 0, stream>>>(pe, W, b, a, ws);
    k2_main<<<K2_BLOCKS, K2_TPB, 0, stream>>>(code, ws);
    k3_agg<<<16, 256, 0, stream>>>(W, b, ws, out);
    k4_logits<<<64, 256, 0, stream>>>(Wc, bc, out);
}

// Round 4
// 177.752 us; speedup vs baseline: 1.8792x; 1.8792x over previous
//
#include <hip/hip_runtime.h>
#include <hip/hip_bf16.h>

#define CODE_DIM 256
#define HIDDEN   128
#define HEADS    4
#define N_CODES  100000
#define N_SPEC   256

// ---- k2 config ----
#define K2_BLOCKS 782                     // 3128 waves; 3125 active, 4 tiles each
#define K2_TPB    256
#define K2_WPB    4
#define K2_AWAVES 3125                    // active waves: 12500 / 4
#define WROWS     8                       // rows per tile
#define NTILES    (N_CODES / WROWS)       // 12500 exact
#define NSLOTS    64

// ---- ws layout (floats) ----
#define WS_V       0                       // v[h][d] : 1024
#define WS_CP      1024                    // c partials [64] (k1 block bx = h*16+dseg)
#define WS_SLOT    1104                    // 64 slots x 1028 (16B aligned)
#define SLOT_STRIDE 1028

#define WAITCNT_LGKM0 0xC07F   // lgkm=0, vmcnt=nowait

// K1 (64 blocks): v[h,d] = W[h,d,:]·a2[h]; c partials; zero slots.
__global__ void k1_prep(const float* __restrict__ pe, const float* __restrict__ W,
                        const float* __restrict__ b, const float* __restrict__ a,
                        float* __restrict__ ws) {
    const int bx = blockIdx.x;            // 64: (h, d-16th)
    const int h = bx >> 4, dseg = bx & 15;
    const int tid = threadIdx.x;
    const int dl = tid >> 4;              // 16 d-values per block
    const int q  = tid & 15;              // 16 k-chunks of 8 elems
    const int d  = dseg * 16 + dl;
    __shared__ float a_sh[2 * HIDDEN];
    __shared__ float cred[4];
    a_sh[tid] = a[h * 2 * HIDDEN + tid];
    __syncthreads();

    const float4* wr = (const float4*)(W + ((size_t)(h * CODE_DIM + d)) * HIDDEN + q * 8);
    float u = 0.f, v = 0.f;
#pragma unroll
    for (int j = 0; j < 2; ++j) {
        float4 wv = wr[j];
        int k = q * 8 + j * 4;
        u += wv.x * a_sh[k]     + wv.y * a_sh[k + 1]
           + wv.z * a_sh[k + 2] + wv.w * a_sh[k + 3];
        v += wv.x * a_sh[HIDDEN + k]     + wv.y * a_sh[HIDDEN + k + 1]
           + wv.z * a_sh[HIDDEN + k + 2] + wv.w * a_sh[HIDDEN + k + 3];
    }
#pragma unroll
    for (int off = 1; off < 16; off <<= 1) {
        u += __shfl_xor(u, off, 64);
        v += __shfl_xor(v, off, 64);
    }
    if (q == 0) ws[WS_V + h * CODE_DIM + d] = v;

    float cp = (q == 0) ? pe[d] * u : 0.f;
    if (dseg == 0 && tid < HIDDEN) cp += b[h * HIDDEN + tid] * (a_sh[tid] + a_sh[HIDDEN + tid]);
#pragma unroll
    for (int off = 32; off; off >>= 1) cp += __shfl_xor(cp, off, 64);
    if ((tid & 63) == 0) cred[tid >> 6] = cp;
    __syncthreads();
    if (tid == 0) ws[WS_CP + bx] = cred[0] + cred[1] + cred[2] + cred[3];

    // zero the 64 atomic slots (k2 depends on stream order)
    float4* z = (float4*)(ws + WS_SLOT);
    const int g = bx * 256 + tid;                 // 16384 threads
    const int nz = (NSLOTS * SLOT_STRIDE) / 4;    // 16448 float4s
    z[g] = make_float4(0.f, 0.f, 0.f, 0.f);
    if (g + 16384 < nz) z[g + 16384] = make_float4(0.f, 0.f, 0.f, 0.f);
}

// K2: streamed global->VGPR pass; value-splitting butterfly reduction; no LDS tiles.
__global__ __launch_bounds__(K2_TPB, 4) void k2_main(const float* __restrict__ code,
                                                     float* __restrict__ ws) {
    __shared__ float t_sh[K2_WPB * 32];
    __shared__ float eps[K2_WPB * HEADS * CODE_DIM];   // 16 KB epilogue staging
    __shared__ float dsh[K2_WPB * HEADS];
    __shared__ float c_sh[HEADS];
    const int tid  = threadIdx.x;
    const int lane = tid & 63;
    const int w    = tid >> 6;
    const int bx   = blockIdx.x;
    const int wid  = bx * K2_WPB + w;

    // reduce the 64 c-partials (16 per head, contiguous)
    if (tid < 64) {
        float cpv = ws[WS_CP + tid];
#pragma unroll
        for (int off = 1; off < 16; off <<= 1) cpv += __shfl_xor(cpv, off, 64);
        if ((tid & 15) == 0) c_sh[tid >> 4] = cpv;
    }
    float4 vh[HEADS];
#pragma unroll
    for (int h = 0; h < HEADS; ++h)
        vh[h] = ((const float4*)(ws + WS_V + h * CODE_DIM))[lane];
    __syncthreads();
    const float cme = c_sh[lane & 3];      // this lane's head offset

    float4 acc0 = make_float4(0,0,0,0), acc1 = acc0, acc2 = acc0, acc3 = acc0;
    float dloc = 0.f;

    for (int tile = wid; tile < NTILES; tile += K2_AWAVES) {
        const float4* rp = (const float4*)(code + (size_t)tile * (WROWS * CODE_DIM));
        float4 x[WROWS];
#pragma unroll
        for (int r = 0; r < WROWS; ++r) x[r] = rp[r * 64 + lane];   // coalesced 1KB/row

        // per-lane partial dots: p[r*4+h] over this lane's 4 cols
        float p[32];
#pragma unroll
        for (int r = 0; r < WROWS; ++r) {
            p[r * 4 + 0] = x[r].x * vh[0].x + x[r].y * vh[0].y + x[r].z * vh[0].z + x[r].w * vh[0].w;
            p[r * 4 + 1] = x[r].x * vh[1].x + x[r].y * vh[1].y + x[r].z * vh[1].z + x[r].w * vh[1].w;
            p[r * 4 + 2] = x[r].x * vh[2].x + x[r].y * vh[2].y + x[r].z * vh[2].z + x[r].w * vh[2].w;
            p[r * 4 + 3] = x[r].x * vh[3].x + x[r].y * vh[3].y + x[r].z * vh[3].z + x[r].w * vh[3].w;
        }
        // value-splitting butterfly: 32 values over 64 lanes -> lane l holds idx l&31
#pragma unroll
        for (int k = 0; k < 5; ++k) {
            const int m = 1 << k;
            const bool hi = (lane & m) != 0;
            const int nv = 16 >> k;
#pragma unroll
            for (int i = 0; i < nv; ++i) {
                float keep = hi ? p[2 * i + 1] : p[2 * i];
                float send = hi ? p[2 * i]     : p[2 * i + 1];
                p[i] = keep + __shfl_xor(send, m, 64);
            }
        }
        float tot = p[0] + __shfl_xor(p[0], 32, 64);   // lane l: full dot for (r,h)=decode(l&31)

        float e = tot + cme;
        e = (e >= 0.f) ? e : 0.2f * e;                 // leaky relu
        float t = __expf(e);                           // un-normalized softmax weight
        dloc += t;                                     // 2x duplicated (lanes & lanes^32)

        if (lane < 32) t_sh[w * 32 + lane] = t;        // banks 0..31, conflict-free
        __builtin_amdgcn_s_waitcnt(WAITCNT_LGKM0);

        // weighted accumulation: lane owns cols 4l..4l+3 (x already in registers)
#pragma unroll
        for (int r = 0; r < WROWS; ++r) {
            float4 tr = *(const float4*)&t_sh[w * 32 + r * 4];   // uniform broadcast
            acc0.x += tr.x * x[r].x; acc0.y += tr.x * x[r].y; acc0.z += tr.x * x[r].z; acc0.w += tr.x * x[r].w;
            acc1.x += tr.y * x[r].x; acc1.y += tr.y * x[r].y; acc1.z += tr.y * x[r].z; acc1.w += tr.y * x[r].w;
            acc2.x += tr.z * x[r].x; acc2.y += tr.z * x[r].y; acc2.z += tr.z * x[r].z; acc2.w += tr.z * x[r].w;
            acc3.x += tr.w * x[r].x; acc3.y += tr.w * x[r].y; acc3.z += tr.w * x[r].z; acc3.w += tr.w * x[r].w;
        }
    }

    // denom: sum dloc over lanes sharing (lane&3); x2 duplication -> scale 0.5
#pragma unroll
    for (int off = 4; off < 64; off <<= 1) dloc += __shfl_xor(dloc, off, 64);
    if (lane < HEADS) dsh[w * HEADS + lane] = dloc * 0.5f;

    // stage per-wave acc, cross-wave reduce, one atomic slot-add per block
    *(float4*)&eps[w * 1024 +   0 + 4 * lane] = acc0;
    *(float4*)&eps[w * 1024 + 256 + 4 * lane] = acc1;
    *(float4*)&eps[w * 1024 + 512 + 4 * lane] = acc2;
    *(float4*)&eps[w * 1024 + 768 + 4 * lane] = acc3;
    __syncthreads();

    float* slot = ws + WS_SLOT + (size_t)(bx & (NSLOTS - 1)) * SLOT_STRIDE;
    for (int o = tid; o < HEADS * CODE_DIM; o += K2_TPB) {
        float s = eps[o] + eps[1024 + o] + eps[2048 + o] + eps[3072 + o];
        atomicAdd(slot + o, s);
    }
    if (tid < HEADS)
        atomicAdd(slot + HEADS * CODE_DIM + tid,
                  dsh[tid] + dsh[4 + tid] + dsh[8 + tid] + dsh[12 + tid]);
}

// K3 (16 blocks): reduce slots -> s[h][:]; normalize; GEMV agg = s@W + b -> mho
__global__ void k3_agg(const float* __restrict__ W, const float* __restrict__ b,
                       const float* __restrict__ ws, float* __restrict__ out) {
    const int bx = blockIdx.x;      // (h, k-quarter)
    const int h = bx >> 2, q = bx & 3;
    const int tid = threadIdx.x;
    __shared__ float s_sh[CODE_DIM];
    __shared__ float yred[8 * 32];
    __shared__ float den_sh;
    const float* slots = ws + WS_SLOT;

    if (tid < 64) {
        float dv = slots[(size_t)tid * SLOT_STRIDE + HEADS * CODE_DIM + h];
#pragma unroll
        for (int off = 32; off; off >>= 1) dv += __shfl_xor(dv, off, 64);
        if (tid == 0) den_sh = dv;
    }
    float su = 0.f;
#pragma unroll 8
    for (int s2 = 0; s2 < NSLOTS; ++s2)
        su += slots[(size_t)s2 * SLOT_STRIDE + h * CODE_DIM + tid];
    __syncthreads();
    s_sh[tid] = su / den_sh;
    __syncthreads();

    const int c = tid >> 5, kl = tid & 31;
    float y = 0.f;
    const float* wp = W + ((size_t)(h * CODE_DIM + c * 32)) * HIDDEN + q * 32 + kl;
#pragma unroll 8
    for (int d = 0; d < 32; ++d) y += s_sh[c * 32 + d] * wp[(size_t)d * HIDDEN];
    yred[c * 32 + kl] = y;
    __syncthreads();
    if (tid < 32) {
        float t = 0.f;
#pragma unroll
        for (int cc = 0; cc < 8; ++cc) t += yred[cc * 32 + tid];
        out[N_SPEC + h * HIDDEN + q * 32 + tid] = t + b[h * HIDDEN + q * 32 + tid];
    }
}

// K4: specialty_logits = Wc @ mho + bc; one wave per logit
__global__ void k4_logits(const float* __restrict__ Wc, const float* __restrict__ bc,
                          float* __restrict__ out) {
    const int lane = threadIdx.x & 63;
    const int wv   = threadIdx.x >> 6;
    const int i    = blockIdx.x * 4 + wv;
    const float4* wr  = (const float4*)(Wc + (size_t)i * (HEADS * HIDDEN));
    const float4* mh4 = (const float4*)(out + N_SPEC);
    float4 wa = wr[lane],      ma = mh4[lane];
    float4 wb = wr[64 + lane], mb = mh4[64 + lane];
    float pp = wa.x * ma.x + wa.y * ma.y + wa.z * ma.z + wa.w * ma.w
             + wb.x * mb.x + wb.y * mb.y + wb.z * mb.z + wb.w * mb.w;
#pragma unroll
    for (int off = 32; off; off >>= 1) pp += __shfl_xor(pp, off, 64);
    if (lane == 0) out[i] = pp + bc[i];
}

extern "C" void kernel_launch(void* const* d_in, const int* in_sizes, int n_in,
                              void* d_out, int out_size, void* d_ws, size_t ws_size,
                              hipStream_t stream) {
    const float* pe   = (const float*)d_in[0];
    const float* code = (const float*)d_in[1];
    const float* W    = (const float*)d_in[2];
    const float* b    = (const float*)d_in[3];
    const float* a    = (const float*)d_in[4];
    const float* Wc   = (const float*)d_in[5];
    const float* bc   = (const float*)d_in[6];
    float* out = (float*)d_out;
    float* ws  = (float*)d_ws;

    k1_prep<<<64, 256, 0, stream>>>(pe, W, b, a, ws);
    k2_main<<<K2_BLOCKS, K2_TPB, 0, stream>>>(code, ws);
    k3_agg<<<16, 256, 0, stream>>>(W, b, ws, out);
    k4_logits<<<64, 256, 0, stream>>>(Wc, bc, out);
}